// Round 12
// baseline (556.532 us; speedup 1.0000x reference)
//
#include <hip/hip_runtime.h>

typedef unsigned short ushort_t;
typedef unsigned short ushort8 __attribute__((ext_vector_type(8)));
typedef __bf16 bf16x8 __attribute__((ext_vector_type(8)));
typedef float f32x4 __attribute__((ext_vector_type(4)));
typedef float f32x16 __attribute__((ext_vector_type(16)));
typedef unsigned uint32x4 __attribute__((ext_vector_type(4)));

#define DEV __device__ __forceinline__

// ---------- helpers ----------
DEV ushort_t f2bf(float f) {
  unsigned u = __builtin_bit_cast(unsigned, f);
  u += 0x7FFFu + ((u >> 16) & 1u);   // RNE (no NaNs in this workload)
  return (ushort_t)(u >> 16);
}
DEV float bf2f(ushort_t u) {
  return __builtin_bit_cast(float, ((unsigned)u) << 16);
}
DEV void gload_lds16(const void* g, void* s) {
  __builtin_amdgcn_global_load_lds(
      (__attribute__((address_space(1))) void*)(size_t)g,
      (__attribute__((address_space(3))) void*)(size_t)s, 16, 0, 0);
}
DEV f32x4 mfma16(ushort8 a, ushort8 b, f32x4 c) {
  return __builtin_amdgcn_mfma_f32_16x16x32_bf16(
      __builtin_bit_cast(bf16x8, a), __builtin_bit_cast(bf16x8, b), c, 0, 0, 0);
}
DEV f32x16 mfma32(ushort8 a, ushort8 b, f32x16 c) {
  return __builtin_amdgcn_mfma_f32_32x32x16_bf16(
      __builtin_bit_cast(bf16x8, a), __builtin_bit_cast(bf16x8, b), c, 0, 0, 0);
}
DEV f32x16 zero16() {
  f32x16 z;
#pragma unroll
  for (int i = 0; i < 16; ++i) z[i] = 0.f;
  return z;
}
DEV unsigned cvtpk(float lo, float hi2) {  // u32 = {bf16(hi2), bf16(lo)}
  unsigned r;
  asm("v_cvt_pk_bf16_f32 %0, %1, %2" : "=v"(r) : "v"(lo), "v"(hi2));
  return r;
}
// x'[l] = l<32 ? x[l] : y[l-32];  y'[l] = l<32 ? x[l+32] : y[l]
DEV void swap32(unsigned &x, unsigned &y) {
#if __has_builtin(__builtin_amdgcn_permlane32_swap)
  auto t = __builtin_amdgcn_permlane32_swap(x, y, false, false);
  x = (unsigned)t[0];
  y = (unsigned)t[1];
#else
  unsigned xs = (unsigned)__shfl_xor((int)x, 32, 64);
  unsigned ys = (unsigned)__shfl_xor((int)y, 32, 64);
  bool h = (threadIdx.x & 63) >= 32;
  unsigned nx = h ? ys : x;
  unsigned ny = h ? y : xs;
  x = nx; y = ny;
#endif
}
DEV void barx() {  // raw barrier, no vmcnt drain; compiler memory fence
  asm volatile("" ::: "memory");
  __builtin_amdgcn_s_barrier();
  asm volatile("" ::: "memory");
}
#define GATE_VM0 asm volatile("s_waitcnt vmcnt(0)" ::: "memory")
#define GATE_VM5 asm volatile("s_waitcnt vmcnt(5)" ::: "memory")
#define GATE_VM8 asm volatile("s_waitcnt vmcnt(8)" ::: "memory")
#define GATE_VM9 asm volatile("s_waitcnt vmcnt(9)" ::: "memory")

// ---------- 1) f32 -> bf16 cast ----------
__global__ void cast_bf16(const float4* __restrict__ in,
                          ushort4* __restrict__ out, int n4) {
  int stride = gridDim.x * blockDim.x;
  for (int i = blockIdx.x * blockDim.x + threadIdx.x; i < n4; i += stride) {
    float4 v = in[i];
    out[i] = make_ushort4(f2bf(v.x), f2bf(v.y), f2bf(v.z), f2bf(v.w));
  }
}

// ---------- 2) GEMM BMxBN, BK=64, 16x16 frags, counted-gate dbuf ----------
// r12 change: gate moved to ITERATION START and made counted -- vmcnt(NST)
// waits only for tile t's loads (issued a full iteration ago), t+1's NST
// loads stay in flight across the whole compute (true T4: never drain).
// Requires per-wave-uniform staging counts: B padded to BNP rows so BCH is
// integral (pad reads stay inside d_ws; pad rows never read).
// Ledger: prologue stages t0->b0, t1->b1. Iter t: gate(VM_NST: all-but-
// newest-9 = t's landed; last iter VM0 since no newer exist) -> barrier
// (publish all waves' slices) -> compute buf[t&1] -> barrier (WAR) ->
// stage t+2 into buf[t&1] (its readers just finished).
// VGPR ledger (r9/r10): WPE caps VGPR at 512/WPE. GEMM1 acc=144 -> WPE=2.
// GEMM2 acc=48 -> WPE=4, LDS 80KB -> 2 blk/CU.
// Chunk swizzle phys = log ^ (row&7), both sides (r8: measured 0 conflicts).
template <int MIW, int NIW, int WPE, int OUT_BF16, int ADD_BIAS>
__global__ __launch_bounds__(512, WPE)
void gemmT(const ushort_t* __restrict__ A, const ushort_t* __restrict__ Bw,
           const float* __restrict__ bias, void* __restrict__ Cp,
           int M, int N, int K) {
  constexpr int BM = MIW * 64;                  // 256 or 128
  constexpr int BN = NIW * 32;                  // 288 or 192
  constexpr int ACH = (BM * 8) / 512;           // A staging instrs (4 or 2)
  constexpr int BCH = (BN * 8 + 511) / 512;     // B staging instrs, ceil (5 or 3)
  constexpr int BNP = BCH * 64;                 // padded B rows (320 or 192)
  constexpr int NST = ACH + BCH;                // 9 or 5 (uniform per wave)
  __shared__ ushort_t As[2][BM * 64];
  __shared__ ushort_t Bs[2][BNP * 64];
  const int tid = threadIdx.x;
  const int w = tid >> 6, l = tid & 63;
  const int g = l >> 4, r = l & 15;
  const int wm = w >> 1, wn = w & 1;
  // XCD-chunked bijective swizzle (nwg % 8 == 0 for both grids)
  const int gx = gridDim.x;
  const int nwg = gx * gridDim.y;
  const int id = blockIdx.y * gx + blockIdx.x;
  const int swz = (id & 7) * (nwg >> 3) + (id >> 3);
  const int m0 = (swz / gx) * BM, n0 = (swz % gx) * BN;
  const int NT = K >> 6;

  // staging: instr i covers chunks [i*512, i*512+512); lane u -> row u>>3,
  // slot u&7; source k-chunk pre-swizzled (u&7)^(row&7)
  auto stA = [&](int i, int t, int b) {
    int u = i * 512 + tid;
    int row = u >> 3;
    gload_lds16(A + (size_t)(m0 + row) * K + t * 64 + (((u & 7) ^ (row & 7)) * 8),
                As[b] + (i * 512 + w * 64) * 8);
  };
  auto stB = [&](int i, int t, int b) {
    int u = i * 512 + tid;
    int row = u >> 3;   // may hit pad rows [BN,BNP): reads stay in d_ws, never consumed
    gload_lds16(Bw + (size_t)(n0 + row) * K + t * 64 + (((u & 7) ^ (row & 7)) * 8),
                Bs[b] + (i * 512 + w * 64) * 8);
  };
  auto stage = [&](int t, int b) {
#pragma unroll
    for (int i = 0; i < ACH; ++i) stA(i, t, b);
#pragma unroll
    for (int i = 0; i < BCH; ++i) stB(i, t, b);
  };
  // 16x16 frag reads (r6/r8 pattern, measured 0 conflicts)
  auto rdA = [&](int b, int mi, int kk) -> ushort8 {
    int row = wm * (MIW * 16) + mi * 16 + r;   // row&7 == r&7
    return *(const ushort8*)(As[b] + row * 64 + ((((kk << 2) + g) ^ (r & 7)) * 8));
  };
  auto rdB = [&](int b, int ni, int kk) -> ushort8 {
    int row = wn * (NIW * 16) + ni * 16 + r;   // NIW*16 % 8 == 0 -> row&7==r&7
    return *(const ushort8*)(Bs[b] + row * 64 + ((((kk << 2) + g) ^ (r & 7)) * 8));
  };

  f32x4 acc[MIW][NIW];
#pragma unroll
  for (int i = 0; i < MIW; ++i)
#pragma unroll
    for (int j = 0; j < NIW; ++j) acc[i][j] = f32x4{0.f, 0.f, 0.f, 0.f};

  // prologue: two tiles in flight
  stage(0, 0);
  if (NT > 1) stage(1, 1);

  for (int t = 0; t < NT; ++t) {
    const int db = t & 1;
    if (t < NT - 1) {
      if constexpr (NST == 9) { GATE_VM9; } else { GATE_VM5; }
    } else {
      GATE_VM0;   // no newer loads exist; counted gate would not wait
    }
    barx();       // all waves' tile-t slices visible
    __builtin_amdgcn_s_setprio(1);
#pragma unroll
    for (int kk = 0; kk < 2; ++kk) {
      ushort8 af[MIW];
#pragma unroll
      for (int mi = 0; mi < MIW; ++mi) af[mi] = rdA(db, mi, kk);
#pragma unroll
      for (int ni = 0; ni < NIW; ++ni) {
        ushort8 b = rdB(db, ni, kk);
#pragma unroll
        for (int mi = 0; mi < MIW; ++mi)
          acc[mi][ni] = mfma16(af[mi], b, acc[mi][ni]);
      }
    }
    __builtin_amdgcn_s_setprio(0);
    barx();       // WAR: buf db's readers (all waves) done
    if (t + 2 < NT) stage(t + 2, db);   // refill the buffer just computed
  }

  // epilogue: D row = 4g+j (M-dim), col = r (N-dim)
#pragma unroll
  for (int mi = 0; mi < MIW; ++mi) {
#pragma unroll
    for (int ni = 0; ni < NIW; ++ni) {
#pragma unroll
      for (int j = 0; j < 4; ++j) {
        int row = m0 + wm * (MIW * 16) + mi * 16 + g * 4 + j;
        int col = n0 + wn * (NIW * 16) + ni * 16 + r;
        float v = acc[mi][ni][j];
        if (ADD_BIAS) v += bias[col];
        if (OUT_BF16)
          ((ushort_t*)Cp)[(size_t)row * N + col] = f2bf(v);
        else
          ((float*)Cp)[(size_t)row * N + col] = v;
      }
    }
  }
}

// ---------- 3) RMSNorm + RoPE (Q,K row-major) + V transpose to [B,H,D,L] ----
__global__ __launch_bounds__(256)
void norm_rope(const ushort_t* __restrict__ qkv, const float* __restrict__ pe,
               const float* __restrict__ qs, const float* __restrict__ ksc,
               ushort_t* __restrict__ qb, ushort_t* __restrict__ kb,
               ushort_t* __restrict__ vtg) {
  __shared__ ushort_t Vt_lds[128 * 64];   // [d][token], XOR-swizzled
  const int tid = threadIdx.x;
  const int w = tid >> 6, lane = tid & 63;
  const int tb = blockIdx.x, h = blockIdx.y;
  const int bl0 = tb * 64;
  const int b = bl0 >> 11, l0 = bl0 & 2047;
  const int i2 = lane * 2;

  const float sq0 = qs[i2], sq1 = qs[i2 + 1];
  const float sk0 = ksc[i2], sk1 = ksc[i2 + 1];
  const float QSC = 0.12751744f;  // log2(e) / sqrt(128): softmax in base-2

  for (int t = 0; t < 16; ++t) {
    const int bl = bl0 + w * 16 + t;
    const float4 p4 = *(const float4*)(pe + (size_t)bl * 256 + lane * 4);
    const size_t src = (size_t)bl * 9216 + h * 128 + i2;
    const size_t dst = ((size_t)(b * 24 + h) * 2048 + (bl & 2047)) * 128 + i2;
    {  // Q
      unsigned u = *(const unsigned*)(qkv + src);
      float x0 = bf2f((ushort_t)(u & 0xFFFFu)), x1 = bf2f((ushort_t)(u >> 16));
      float ss = x0 * x0 + x1 * x1;
#pragma unroll
      for (int mm = 32; mm; mm >>= 1) ss += __shfl_xor(ss, mm, 64);
      float rr = rsqrtf(ss * (1.f / 128.f) + 1e-6f);
      float y0 = x0 * rr * sq0, y1 = x1 * rr * sq1;
      float o0 = (p4.x * y0 + p4.y * y1) * QSC;
      float o1 = (p4.z * y0 + p4.w * y1) * QSC;
      *(unsigned*)(qb + dst) = (unsigned)f2bf(o0) | ((unsigned)f2bf(o1) << 16);
    }
    {  // K
      unsigned u = *(const unsigned*)(qkv + src + 3072);
      float x0 = bf2f((ushort_t)(u & 0xFFFFu)), x1 = bf2f((ushort_t)(u >> 16));
      float ss = x0 * x0 + x1 * x1;
#pragma unroll
      for (int mm = 32; mm; mm >>= 1) ss += __shfl_xor(ss, mm, 64);
      float rr = rsqrtf(ss * (1.f / 128.f) + 1e-6f);
      float y0 = x0 * rr * sk0, y1 = x1 * rr * sk1;
      float o0 = p4.x * y0 + p4.y * y1;
      float o1 = p4.z * y0 + p4.w * y1;
      *(unsigned*)(kb + dst) = (unsigned)f2bf(o0) | ((unsigned)f2bf(o1) << 16);
    }
  }

  {  // V -> LDS transposed
    const ushort_t* vsrc = qkv + (size_t)(bl0 + lane) * 9216 + 6144 + h * 128;
#pragma unroll
    for (int i = 0; i < 4; ++i) {
      int oct = w * 4 + i;
      ushort8 vv = *(const ushort8*)(vsrc + oct * 8);
#pragma unroll
      for (int j = 0; j < 8; ++j) {
        int d = oct * 8 + j;
        int ba = (d * 128 + lane * 2) ^ (j << 4);
        *(ushort_t*)((char*)Vt_lds + ba) = vv[j];
      }
    }
  }
  __syncthreads();

  {  // coalesced V^T rows to global [B,H,D,L]
    const int d = tid >> 1, half = tid & 1;
    ushort_t* orow = vtg + ((size_t)(b * 24 + h) * 128 + d) * 2048 + l0 + half * 32;
#pragma unroll
    for (int q = 0; q < 4; ++q) {
      int lb = d * 128 + half * 64 + q * 16;
      ushort8 vv = *(const ushort8*)((char*)Vt_lds + (lb ^ ((d & 7) << 4)));
      *(ushort8*)(orow + q * 8) = vv;
    }
  }
}

// ---------- 4) flash attention: swapped 32x32, double-buffered K/V ----------
// r8-proven structure. __launch_bounds__(256,2): VGPR cap 256, no spill;
// LDS 64KB, 2 blk/CU. Per tile: stage K(t+1),V(t+1) -> buf db^1; gate vm8
// (t's 8 landed, t+1's in flight across compute); barrier; QK^T; softmax;
// cvt_pk/permlane; PV; barrier (WAR guard).
__global__ __launch_bounds__(256, 2)
void attn_fwd(const ushort_t* __restrict__ qb, const ushort_t* __restrict__ kb,
              const ushort_t* __restrict__ vt, ushort_t* __restrict__ ob) {
  __shared__ ushort_t Ks[2][64 * 128];    // [key][d], phys chunk = log ^ (key&15)
  __shared__ ushort_t Vts[2][128 * 64];   // [d][key], phys chunk = log ^ (d&7)
  const int tid = threadIdx.x;
  const int w = tid >> 6, l = tid & 63;
  const int c = l & 31, hi = l >> 5;
  // XCD-chunked swizzle (768 blocks, 16 q-tiles x 48 bh)
  const int id = blockIdx.y * 16 + blockIdx.x;
  const int swz = (id & 7) * 96 + (id >> 3);
  const int bh = swz >> 4;
  const int q0 = (swz & 15) * 128 + w * 32;

  const ushort_t* qrow = qb + ((size_t)bh * 2048 + q0 + c) * 128;
  ushort8 qf[8];
#pragma unroll
  for (int s = 0; s < 8; ++s)
    qf[s] = *(const ushort8*)(qrow + s * 16 + hi * 8);

  f32x16 o[4];
#pragma unroll
  for (int dt = 0; dt < 4; ++dt) o[dt] = zero16();
  float m = -1e30f, lp = 0.f;   // m wave-uniform; lp row-c partial sum

  const ushort_t* kbase = kb + (size_t)bh * 2048 * 128;
  const ushort_t* vbase = vt + (size_t)bh * 128 * 2048;

  auto stage = [&](int t, int b) {
#pragma unroll
    for (int i = 0; i < 4; ++i) {
      int u = w * 256 + i * 64 + l;
      int kr = u >> 4, kc = (u & 15) ^ (kr & 15);
      gload_lds16(kbase + (size_t)(t * 64 + kr) * 128 + kc * 8,
                  Ks[b] + (w * 256 + i * 64) * 8);
      int vr = u >> 3, vc = (u & 7) ^ (vr & 7);
      gload_lds16(vbase + (size_t)vr * 2048 + t * 64 + vc * 8,
                  Vts[b] + (w * 256 + i * 64) * 8);
    }
  };

  stage(0, 0);   // prologue

  for (int t = 0; t < 32; ++t) {
    const int db = t & 1;
    if (t < 31) {
      stage(t + 1, db ^ 1);
      GATE_VM8;          // drains tile t's 8; t+1's stay in flight
    } else {
      GATE_VM0;
    }
    barx();

    // S^T = K . Q^T : two 32-key tiles, 8 d-steps of k=16
    f32x16 s0 = zero16(), s1 = zero16();
    __builtin_amdgcn_s_setprio(1);
#pragma unroll
    for (int ds = 0; ds < 8; ++ds) {
      int ch = (2 * ds + hi) ^ (c & 15);
      ushort8 k0 = *(const ushort8*)(Ks[db] + c * 128 + ch * 8);
      ushort8 k1 = *(const ushort8*)(Ks[db] + (32 + c) * 128 + ch * 8);
      s0 = mfma32(k0, qf[ds], s0);
      s1 = mfma32(k1, qf[ds], s1);
    }
    __builtin_amdgcn_s_setprio(0);

    // online softmax (base-2), wave-uniform max, defer THR=8; in-place s0/s1
    float pmax = s0[0];
#pragma unroll
    for (int rr = 1; rr < 16; ++rr) pmax = fmaxf(pmax, s0[rr]);
#pragma unroll
    for (int rr = 0; rr < 16; ++rr) pmax = fmaxf(pmax, s1[rr]);
    if (!__all(pmax <= m + 8.f)) {
      float wm2 = pmax;
#pragma unroll
      for (int d = 1; d < 64; d <<= 1) wm2 = fmaxf(wm2, __shfl_xor(wm2, d, 64));
      float mn = fmaxf(m, wm2);       // wave-uniform new max
      float fs = exp2f(m - mn);       // layout-independent rescale
      m = mn;
      lp *= fs;
#pragma unroll
      for (int dt = 0; dt < 4; ++dt)
#pragma unroll
        for (int e = 0; e < 16; ++e) o[dt][e] *= fs;
    }
    float rs = 0.f;
#pragma unroll
    for (int rr = 0; rr < 16; ++rr) { s0[rr] = exp2f(s0[rr] - m); rs += s0[rr]; }
#pragma unroll
    for (int rr = 0; rr < 16; ++rr) { s1[rr] = exp2f(s1[rr] - m); rs += s1[rr]; }
    lp += rs;

    // P -> A-frag words: 4 cvt_pk + 2 permlane32_swap per 16-key step (T12)
    uint32x4 pk[4];
#pragma unroll
    for (int ks = 0; ks < 2; ++ks) {
      unsigned a0 = cvtpk(s0[ks * 8 + 0], s0[ks * 8 + 1]);
      unsigned a1 = cvtpk(s0[ks * 8 + 2], s0[ks * 8 + 3]);
      unsigned a2 = cvtpk(s0[ks * 8 + 4], s0[ks * 8 + 5]);
      unsigned a3 = cvtpk(s0[ks * 8 + 6], s0[ks * 8 + 7]);
      swap32(a0, a2);
      swap32(a1, a3);
      pk[ks] = uint32x4{a0, a1, a2, a3};
    }
#pragma unroll
    for (int ks = 0; ks < 2; ++ks) {
      unsigned a0 = cvtpk(s1[ks * 8 + 0], s1[ks * 8 + 1]);
      unsigned a1 = cvtpk(s1[ks * 8 + 2], s1[ks * 8 + 3]);
      unsigned a2 = cvtpk(s1[ks * 8 + 4], s1[ks * 8 + 5]);
      unsigned a3 = cvtpk(s1[ks * 8 + 6], s1[ks * 8 + 7]);
      swap32(a0, a2);
      swap32(a1, a3);
      pk[2 + ks] = uint32x4{a0, a1, a2, a3};
    }

    // O += P . V
    __builtin_amdgcn_s_setprio(1);
#pragma unroll
    for (int dt = 0; dt < 4; ++dt) {
#pragma unroll
      for (int ks = 0; ks < 4; ++ks) {
        int ch = (2 * ks + hi) ^ (c & 7);
        ushort8 vf = *(const ushort8*)(Vts[db] + (32 * dt + c) * 64 + ch * 8);
        o[dt] = mfma32(__builtin_bit_cast(ushort8, pk[ks]), vf, o[dt]);
      }
    }
    __builtin_amdgcn_s_setprio(0);
    barx();   // WAR guard: next iter stages into buf db
  }

  // epilogue: lr lives at lane q (row c); O rows are crow(r,hi) -> shfl
  float lr = lp + __shfl_xor(lp, 32, 64);
  float rl = 1.f / lr;
  const int b = bh / 24, h = bh % 24;
  ushort_t* obase = ob + ((size_t)b * 2048 + q0) * 3072 + h * 128 + c;
#pragma unroll
  for (int rr = 0; rr < 16; ++rr) {
    int q = (rr & 3) + 8 * (rr >> 2) + 4 * hi;
    float os = __shfl(rl, q, 64);   // denominator of row q
#pragma unroll
    for (int dt = 0; dt < 4; ++dt)
      obase[(size_t)q * 3072 + dt * 32] = f2bf(o[dt][rr] * os);
  }
}

// ---------- launch ----------
extern "C" void kernel_launch(void* const* d_in, const int* in_sizes, int n_in,
                              void* d_out, int out_size, void* d_ws, size_t ws_size,
                              hipStream_t stream) {
  const float* x    = (const float*)d_in[0];
  const float* pe   = (const float*)d_in[1];
  const float* qkvw = (const float*)d_in[2];
  const float* pw   = (const float*)d_in[3];
  const float* pb   = (const float*)d_in[4];
  const float* qsc  = (const float*)d_in[5];
  const float* ksc  = (const float*)d_in[6];
  float* out = (float*)d_out;

  char* p = (char*)d_ws;
  ushort_t* x_bf  = (ushort_t*)(p + 0);          // 25,165,824
  ushort_t* o_bf  = x_bf;                        // reuse: x dead after GEMM1
  ushort_t* qw_bf = (ushort_t*)(p + 25165824);   // 56,623,104
  ushort_t* pw_bf = (ushort_t*)(p + 81788928);   // 18,874,368
  ushort_t* qkv   = (ushort_t*)(p + 100663296);  // 75,497,472
  ushort_t* qh    = (ushort_t*)(p + 176160768);  // 25,165,824
  ushort_t* kh    = (ushort_t*)(p + 201326592);  // 25,165,824
  ushort_t* vtg   = (ushort_t*)(p + 226492416);  // 25,165,824 (V^T [B,H,D,L])

  cast_bf16<<<2048, 256, 0, stream>>>((const float4*)x,    (ushort4*)x_bf,  4096 * 3072 / 4);
  cast_bf16<<<2048, 256, 0, stream>>>((const float4*)qkvw, (ushort4*)qw_bf, 9216 * 3072 / 4);
  cast_bf16<<<2048, 256, 0, stream>>>((const float4*)pw,   (ushort4*)pw_bf, 3072 * 3072 / 4);

  // GEMM1: BM=256,BN=288 (B padded to 320 rows in LDS), WPE=2, grid 512=2.00/CU
  gemmT<4, 9, 2, 1, 0><<<dim3(32, 16), 512, 0, stream>>>(x_bf, qw_bf, nullptr, qkv, 4096, 9216, 3072);
  norm_rope<<<dim3(64, 24), 256, 0, stream>>>(qkv, pe, qsc, ksc, qh, kh, vtg);
  attn_fwd<<<dim3(16, 48), 256, 0, stream>>>(qh, kh, vtg, o_bf);
  // GEMM2: BM=128,BN=192,WPE=4 -> LDS 80KB, 2 blk/CU, grid 512 = 2.00/CU
  gemmT<2, 6, 4, 0, 1><<<dim3(16, 32), 512, 0, stream>>>(o_bf, pw_bf, pb, out, 4096, 3072, 3072);
}

// Round 13
// 518.825 us; speedup vs baseline: 1.0727x; 1.0727x over previous
//
#include <hip/hip_runtime.h>

typedef unsigned short ushort_t;
typedef unsigned short ushort8 __attribute__((ext_vector_type(8)));
typedef __bf16 bf16x8 __attribute__((ext_vector_type(8)));
typedef float f32x4 __attribute__((ext_vector_type(4)));
typedef float f32x16 __attribute__((ext_vector_type(16)));
typedef unsigned uint32x4 __attribute__((ext_vector_type(4)));

#define DEV __device__ __forceinline__

// ---------- helpers ----------
DEV ushort_t f2bf(float f) {
  unsigned u = __builtin_bit_cast(unsigned, f);
  u += 0x7FFFu + ((u >> 16) & 1u);   // RNE (no NaNs in this workload)
  return (ushort_t)(u >> 16);
}
DEV float bf2f(ushort_t u) {
  return __builtin_bit_cast(float, ((unsigned)u) << 16);
}
DEV void gload_lds16(const void* g, void* s) {
  __builtin_amdgcn_global_load_lds(
      (__attribute__((address_space(1))) void*)(size_t)g,
      (__attribute__((address_space(3))) void*)(size_t)s, 16, 0, 0);
}
DEV f32x4 mfma16(ushort8 a, ushort8 b, f32x4 c) {
  return __builtin_amdgcn_mfma_f32_16x16x32_bf16(
      __builtin_bit_cast(bf16x8, a), __builtin_bit_cast(bf16x8, b), c, 0, 0, 0);
}
DEV f32x16 mfma32(ushort8 a, ushort8 b, f32x16 c) {
  return __builtin_amdgcn_mfma_f32_32x32x16_bf16(
      __builtin_bit_cast(bf16x8, a), __builtin_bit_cast(bf16x8, b), c, 0, 0, 0);
}
DEV f32x16 zero16() {
  f32x16 z;
#pragma unroll
  for (int i = 0; i < 16; ++i) z[i] = 0.f;
  return z;
}
DEV unsigned cvtpk(float lo, float hi2) {  // u32 = {bf16(hi2), bf16(lo)}
  unsigned r;
  asm("v_cvt_pk_bf16_f32 %0, %1, %2" : "=v"(r) : "v"(lo), "v"(hi2));
  return r;
}
// x'[l] = l<32 ? x[l] : y[l-32];  y'[l] = l<32 ? x[l+32] : y[l]
DEV void swap32(unsigned &x, unsigned &y) {
#if __has_builtin(__builtin_amdgcn_permlane32_swap)
  auto t = __builtin_amdgcn_permlane32_swap(x, y, false, false);
  x = (unsigned)t[0];
  y = (unsigned)t[1];
#else
  unsigned xs = (unsigned)__shfl_xor((int)x, 32, 64);
  unsigned ys = (unsigned)__shfl_xor((int)y, 32, 64);
  bool h = (threadIdx.x & 63) >= 32;
  unsigned nx = h ? ys : x;
  unsigned ny = h ? y : xs;
  x = nx; y = ny;
#endif
}
DEV void barx() {  // raw barrier, no vmcnt drain; compiler memory fence
  asm volatile("" ::: "memory");
  __builtin_amdgcn_s_barrier();
  asm volatile("" ::: "memory");
}
#define GATE_VM0 asm volatile("s_waitcnt vmcnt(0)" ::: "memory")
#define GATE_VM8 asm volatile("s_waitcnt vmcnt(8)" ::: "memory")

// ---------- 1) f32 -> bf16 cast ----------
__global__ void cast_bf16(const float4* __restrict__ in,
                          ushort4* __restrict__ out, int n4) {
  int stride = gridDim.x * blockDim.x;
  for (int i = blockIdx.x * blockDim.x + threadIdx.x; i < n4; i += stride) {
    float4 v = in[i];
    out[i] = make_ushort4(f2bf(v.x), f2bf(v.y), f2bf(v.z), f2bf(v.w));
  }
}

// ---------- 2) GEMM 256xBN, 16x16 frags, 1-barrier dbuf (r8-proven) -------
// BN=288 for GEMM1 (grid 32x16=512 = 2.00 dispatch rounds at 1 blk/CU),
// BN=192 for GEMM2 (grid 16x16=256 = 1.00/CU). 8 waves 4M x 2N.
// Ledger: iter t stages t+1 -> buf db^1 BEFORE compute (issue overlaps
// MFMA; r12 showed stage-after-compute serializes and loses ~12%);
// compute tile t; vmcnt(0) (loads issued a full compute phase ago ->
// latency hidden); s_barrier. Chunk swizzle phys = log ^ (row&7), both
// sides (measured 0 conflicts). WPE=2: VGPR cap 256, acc=144 fits.
template <int NIW, int OUT_BF16, int ADD_BIAS>
__global__ __launch_bounds__(512, 2)
void gemmT(const ushort_t* __restrict__ A, const ushort_t* __restrict__ Bw,
           const float* __restrict__ bias, void* __restrict__ Cp,
           int M, int N, int K) {
  constexpr int BN = NIW * 32;            // 288 or 192
  constexpr int BCH_FULL = (BN * 8) / 512;      // full B staging instrs
  constexpr int BCH_TAIL = (BN * 8) % 512;      // leftover chunks (0 or 256)
  __shared__ ushort_t As[2][256 * 64];
  __shared__ ushort_t Bs[2][BN * 64];
  const int tid = threadIdx.x;
  const int w = tid >> 6, l = tid & 63;
  const int g = l >> 4, r = l & 15;
  const int wm = w >> 1, wn = w & 1;
  // XCD-chunked bijective swizzle (nwg % 8 == 0 for both grids)
  const int gx = gridDim.x;
  const int nwg = gx * gridDim.y;
  const int id = blockIdx.y * gx + blockIdx.x;
  const int swz = (id & 7) * (nwg >> 3) + (id >> 3);
  const int m0 = (swz / gx) * 256, n0 = (swz % gx) * BN;
  const int NT = K >> 6;

  // staging: instr i covers chunks [i*512, i*512+512); lane u -> row u>>3,
  // slot u&7; source k-chunk pre-swizzled (u&7)^(row&7)
  auto stA = [&](int i, int t, int b) {
    int u = i * 512 + tid;
    int row = u >> 3;
    gload_lds16(A + (size_t)(m0 + row) * K + t * 64 + (((u & 7) ^ (row & 7)) * 8),
                As[b] + (i * 512 + w * 64) * 8);
  };
  auto stB = [&](int i, int t, int b) {
    int u = i * 512 + tid;
    int row = u >> 3;
    gload_lds16(Bw + (size_t)(n0 + row) * K + t * 64 + (((u & 7) ^ (row & 7)) * 8),
                Bs[b] + (i * 512 + w * 64) * 8);
  };
  auto stage = [&](int t, int b) {
#pragma unroll
    for (int i = 0; i < 4; ++i) stA(i, t, b);
#pragma unroll
    for (int i = 0; i < BCH_FULL; ++i) stB(i, t, b);
    if (BCH_TAIL && w < (BCH_TAIL >> 6)) stB(BCH_FULL, t, b);
  };
  // 16x16 frag reads (measured 0 conflicts)
  auto rdA = [&](int b, int mi, int kk) -> ushort8 {
    int row = wm * 64 + mi * 16 + r;   // row&7 == r&7
    return *(const ushort8*)(As[b] + row * 64 + ((((kk << 2) + g) ^ (r & 7)) * 8));
  };
  auto rdB = [&](int b, int ni, int kk) -> ushort8 {
    int row = wn * (NIW * 16) + ni * 16 + r;   // NIW*16 % 8 == 0 -> row&7==r&7
    return *(const ushort8*)(Bs[b] + row * 64 + ((((kk << 2) + g) ^ (r & 7)) * 8));
  };

  f32x4 acc[4][NIW];
#pragma unroll
  for (int i = 0; i < 4; ++i)
#pragma unroll
    for (int j = 0; j < NIW; ++j) acc[i][j] = f32x4{0.f, 0.f, 0.f, 0.f};

  // prologue
  stage(0, 0);
  GATE_VM0;
  barx();

  for (int t = 0; t < NT; ++t) {
    const int db = t & 1;
    const bool pre = (t + 1 < NT);
    if (pre) stage(t + 1, db ^ 1);   // issue first: overlaps MFMA below
    asm volatile("" ::: "memory");
    __builtin_amdgcn_s_setprio(1);
#pragma unroll
    for (int kk = 0; kk < 2; ++kk) {
      ushort8 af[4];
#pragma unroll
      for (int mi = 0; mi < 4; ++mi) af[mi] = rdA(db, mi, kk);
#pragma unroll
      for (int ni = 0; ni < NIW; ++ni) {
        ushort8 b = rdB(db, ni, kk);
        acc[0][ni] = mfma16(af[0], b, acc[0][ni]);
        acc[1][ni] = mfma16(af[1], b, acc[1][ni]);
        acc[2][ni] = mfma16(af[2], b, acc[2][ni]);
        acc[3][ni] = mfma16(af[3], b, acc[3][ni]);
      }
    }
    __builtin_amdgcn_s_setprio(0);
    if (pre) GATE_VM0;   // t+1 landed; issued a full compute phase ago
    barx();              // buf db free for t+2's staging
  }

  // epilogue: D row = 4g+j (M-dim), col = r (N-dim)
#pragma unroll
  for (int mi = 0; mi < 4; ++mi) {
#pragma unroll
    for (int ni = 0; ni < NIW; ++ni) {
#pragma unroll
      for (int j = 0; j < 4; ++j) {
        int row = m0 + wm * 64 + mi * 16 + g * 4 + j;
        int col = n0 + wn * (NIW * 16) + ni * 16 + r;
        float v = acc[mi][ni][j];
        if (ADD_BIAS) v += bias[col];
        if (OUT_BF16)
          ((ushort_t*)Cp)[(size_t)row * N + col] = f2bf(v);
        else
          ((float*)Cp)[(size_t)row * N + col] = v;
      }
    }
  }
}

// ---------- 3) RMSNorm + RoPE (Q,K row-major) + V transpose to [B,H,D,L] ----
__global__ __launch_bounds__(256)
void norm_rope(const ushort_t* __restrict__ qkv, const float* __restrict__ pe,
               const float* __restrict__ qs, const float* __restrict__ ksc,
               ushort_t* __restrict__ qb, ushort_t* __restrict__ kb,
               ushort_t* __restrict__ vtg) {
  __shared__ ushort_t Vt_lds[128 * 64];   // [d][token], XOR-swizzled
  const int tid = threadIdx.x;
  const int w = tid >> 6, lane = tid & 63;
  const int tb = blockIdx.x, h = blockIdx.y;
  const int bl0 = tb * 64;
  const int b = bl0 >> 11, l0 = bl0 & 2047;
  const int i2 = lane * 2;

  const float sq0 = qs[i2], sq1 = qs[i2 + 1];
  const float sk0 = ksc[i2], sk1 = ksc[i2 + 1];
  const float QSC = 0.12751744f;  // log2(e) / sqrt(128): softmax in base-2

  for (int t = 0; t < 16; ++t) {
    const int bl = bl0 + w * 16 + t;
    const float4 p4 = *(const float4*)(pe + (size_t)bl * 256 + lane * 4);
    const size_t src = (size_t)bl * 9216 + h * 128 + i2;
    const size_t dst = ((size_t)(b * 24 + h) * 2048 + (bl & 2047)) * 128 + i2;
    {  // Q
      unsigned u = *(const unsigned*)(qkv + src);
      float x0 = bf2f((ushort_t)(u & 0xFFFFu)), x1 = bf2f((ushort_t)(u >> 16));
      float ss = x0 * x0 + x1 * x1;
#pragma unroll
      for (int mm = 32; mm; mm >>= 1) ss += __shfl_xor(ss, mm, 64);
      float rr = rsqrtf(ss * (1.f / 128.f) + 1e-6f);
      float y0 = x0 * rr * sq0, y1 = x1 * rr * sq1;
      float o0 = (p4.x * y0 + p4.y * y1) * QSC;
      float o1 = (p4.z * y0 + p4.w * y1) * QSC;
      *(unsigned*)(qb + dst) = (unsigned)f2bf(o0) | ((unsigned)f2bf(o1) << 16);
    }
    {  // K
      unsigned u = *(const unsigned*)(qkv + src + 3072);
      float x0 = bf2f((ushort_t)(u & 0xFFFFu)), x1 = bf2f((ushort_t)(u >> 16));
      float ss = x0 * x0 + x1 * x1;
#pragma unroll
      for (int mm = 32; mm; mm >>= 1) ss += __shfl_xor(ss, mm, 64);
      float rr = rsqrtf(ss * (1.f / 128.f) + 1e-6f);
      float y0 = x0 * rr * sk0, y1 = x1 * rr * sk1;
      float o0 = p4.x * y0 + p4.y * y1;
      float o1 = p4.z * y0 + p4.w * y1;
      *(unsigned*)(kb + dst) = (unsigned)f2bf(o0) | ((unsigned)f2bf(o1) << 16);
    }
  }

  {  // V -> LDS transposed
    const ushort_t* vsrc = qkv + (size_t)(bl0 + lane) * 9216 + 6144 + h * 128;
#pragma unroll
    for (int i = 0; i < 4; ++i) {
      int oct = w * 4 + i;
      ushort8 vv = *(const ushort8*)(vsrc + oct * 8);
#pragma unroll
      for (int j = 0; j < 8; ++j) {
        int d = oct * 8 + j;
        int ba = (d * 128 + lane * 2) ^ (j << 4);
        *(ushort_t*)((char*)Vt_lds + ba) = vv[j];
      }
    }
  }
  __syncthreads();

  {  // coalesced V^T rows to global [B,H,D,L]
    const int d = tid >> 1, half = tid & 1;
    ushort_t* orow = vtg + ((size_t)(b * 24 + h) * 128 + d) * 2048 + l0 + half * 32;
#pragma unroll
    for (int q = 0; q < 4; ++q) {
      int lb = d * 128 + half * 64 + q * 16;
      ushort8 vv = *(const ushort8*)((char*)Vt_lds + (lb ^ ((d & 7) << 4)));
      *(ushort8*)(orow + q * 8) = vv;
    }
  }
}

// ---------- 4) flash attention: swapped 32x32, double-buffered K/V ----------
// r8-proven. __launch_bounds__(256,2): VGPR cap 256, no spill; LDS 64KB,
// 2 blk/CU. Per tile: stage K(t+1),V(t+1) -> buf db^1; gate vm8 (t's 8
// landed, t+1's in flight across compute); barrier; QK^T; softmax;
// cvt_pk/permlane; PV; barrier (WAR guard).
__global__ __launch_bounds__(256, 2)
void attn_fwd(const ushort_t* __restrict__ qb, const ushort_t* __restrict__ kb,
              const ushort_t* __restrict__ vt, ushort_t* __restrict__ ob) {
  __shared__ ushort_t Ks[2][64 * 128];    // [key][d], phys chunk = log ^ (key&15)
  __shared__ ushort_t Vts[2][128 * 64];   // [d][key], phys chunk = log ^ (d&7)
  const int tid = threadIdx.x;
  const int w = tid >> 6, l = tid & 63;
  const int c = l & 31, hi = l >> 5;
  // XCD-chunked swizzle (768 blocks, 16 q-tiles x 48 bh)
  const int id = blockIdx.y * 16 + blockIdx.x;
  const int swz = (id & 7) * 96 + (id >> 3);
  const int bh = swz >> 4;
  const int q0 = (swz & 15) * 128 + w * 32;

  const ushort_t* qrow = qb + ((size_t)bh * 2048 + q0 + c) * 128;
  ushort8 qf[8];
#pragma unroll
  for (int s = 0; s < 8; ++s)
    qf[s] = *(const ushort8*)(qrow + s * 16 + hi * 8);

  f32x16 o[4];
#pragma unroll
  for (int dt = 0; dt < 4; ++dt) o[dt] = zero16();
  float m = -1e30f, lp = 0.f;   // m wave-uniform; lp row-c partial sum

  const ushort_t* kbase = kb + (size_t)bh * 2048 * 128;
  const ushort_t* vbase = vt + (size_t)bh * 128 * 2048;

  auto stage = [&](int t, int b) {
#pragma unroll
    for (int i = 0; i < 4; ++i) {
      int u = w * 256 + i * 64 + l;
      int kr = u >> 4, kc = (u & 15) ^ (kr & 15);
      gload_lds16(kbase + (size_t)(t * 64 + kr) * 128 + kc * 8,
                  Ks[b] + (w * 256 + i * 64) * 8);
      int vr = u >> 3, vc = (u & 7) ^ (vr & 7);
      gload_lds16(vbase + (size_t)vr * 2048 + t * 64 + vc * 8,
                  Vts[b] + (w * 256 + i * 64) * 8);
    }
  };

  stage(0, 0);   // prologue

  for (int t = 0; t < 32; ++t) {
    const int db = t & 1;
    if (t < 31) {
      stage(t + 1, db ^ 1);
      GATE_VM8;          // drains tile t's 8; t+1's stay in flight
    } else {
      GATE_VM0;
    }
    barx();

    // S^T = K . Q^T : two 32-key tiles, 8 d-steps of k=16
    f32x16 s0 = zero16(), s1 = zero16();
    __builtin_amdgcn_s_setprio(1);
#pragma unroll
    for (int ds = 0; ds < 8; ++ds) {
      int ch = (2 * ds + hi) ^ (c & 15);
      ushort8 k0 = *(const ushort8*)(Ks[db] + c * 128 + ch * 8);
      ushort8 k1 = *(const ushort8*)(Ks[db] + (32 + c) * 128 + ch * 8);
      s0 = mfma32(k0, qf[ds], s0);
      s1 = mfma32(k1, qf[ds], s1);
    }
    __builtin_amdgcn_s_setprio(0);

    // online softmax (base-2), wave-uniform max, defer THR=8; in-place s0/s1
    float pmax = s0[0];
#pragma unroll
    for (int rr = 1; rr < 16; ++rr) pmax = fmaxf(pmax, s0[rr]);
#pragma unroll
    for (int rr = 0; rr < 16; ++rr) pmax = fmaxf(pmax, s1[rr]);
    if (!__all(pmax <= m + 8.f)) {
      float wm2 = pmax;
#pragma unroll
      for (int d = 1; d < 64; d <<= 1) wm2 = fmaxf(wm2, __shfl_xor(wm2, d, 64));
      float mn = fmaxf(m, wm2);       // wave-uniform new max
      float fs = exp2f(m - mn);       // layout-independent rescale
      m = mn;
      lp *= fs;
#pragma unroll
      for (int dt = 0; dt < 4; ++dt)
#pragma unroll
        for (int e = 0; e < 16; ++e) o[dt][e] *= fs;
    }
    float rs = 0.f;
#pragma unroll
    for (int rr = 0; rr < 16; ++rr) { s0[rr] = exp2f(s0[rr] - m); rs += s0[rr]; }
#pragma unroll
    for (int rr = 0; rr < 16; ++rr) { s1[rr] = exp2f(s1[rr] - m); rs += s1[rr]; }
    lp += rs;

    // P -> A-frag words: 4 cvt_pk + 2 permlane32_swap per 16-key step (T12)
    uint32x4 pk[4];
#pragma unroll
    for (int ks = 0; ks < 2; ++ks) {
      unsigned a0 = cvtpk(s0[ks * 8 + 0], s0[ks * 8 + 1]);
      unsigned a1 = cvtpk(s0[ks * 8 + 2], s0[ks * 8 + 3]);
      unsigned a2 = cvtpk(s0[ks * 8 + 4], s0[ks * 8 + 5]);
      unsigned a3 = cvtpk(s0[ks * 8 + 6], s0[ks * 8 + 7]);
      swap32(a0, a2);
      swap32(a1, a3);
      pk[ks] = uint32x4{a0, a1, a2, a3};
    }
#pragma unroll
    for (int ks = 0; ks < 2; ++ks) {
      unsigned a0 = cvtpk(s1[ks * 8 + 0], s1[ks * 8 + 1]);
      unsigned a1 = cvtpk(s1[ks * 8 + 2], s1[ks * 8 + 3]);
      unsigned a2 = cvtpk(s1[ks * 8 + 4], s1[ks * 8 + 5]);
      unsigned a3 = cvtpk(s1[ks * 8 + 6], s1[ks * 8 + 7]);
      swap32(a0, a2);
      swap32(a1, a3);
      pk[2 + ks] = uint32x4{a0, a1, a2, a3};
    }

    // O += P . V
    __builtin_amdgcn_s_setprio(1);
#pragma unroll
    for (int dt = 0; dt < 4; ++dt) {
#pragma unroll
      for (int ks = 0; ks < 4; ++ks) {
        int ch = (2 * ks + hi) ^ (c & 7);
        ushort8 vf = *(const ushort8*)(Vts[db] + (32 * dt + c) * 64 + ch * 8);
        o[dt] = mfma32(__builtin_bit_cast(ushort8, pk[ks]), vf, o[dt]);
      }
    }
    __builtin_amdgcn_s_setprio(0);
    barx();   // WAR guard: next iter stages into buf db
  }

  // epilogue: lr lives at lane q (row c); O rows are crow(r,hi) -> shfl
  float lr = lp + __shfl_xor(lp, 32, 64);
  float rl = 1.f / lr;
  const int b = bh / 24, h = bh % 24;
  ushort_t* obase = ob + ((size_t)b * 2048 + q0) * 3072 + h * 128 + c;
#pragma unroll
  for (int rr = 0; rr < 16; ++rr) {
    int q = (rr & 3) + 8 * (rr >> 2) + 4 * hi;
    float os = __shfl(rl, q, 64);   // denominator of row q
#pragma unroll
    for (int dt = 0; dt < 4; ++dt)
      obase[(size_t)q * 3072 + dt * 32] = f2bf(o[dt][rr] * os);
  }
}

// ---------- launch ----------
extern "C" void kernel_launch(void* const* d_in, const int* in_sizes, int n_in,
                              void* d_out, int out_size, void* d_ws, size_t ws_size,
                              hipStream_t stream) {
  const float* x    = (const float*)d_in[0];
  const float* pe   = (const float*)d_in[1];
  const float* qkvw = (const float*)d_in[2];
  const float* pw   = (const float*)d_in[3];
  const float* pb   = (const float*)d_in[4];
  const float* qsc  = (const float*)d_in[5];
  const float* ksc  = (const float*)d_in[6];
  float* out = (float*)d_out;

  char* p = (char*)d_ws;
  ushort_t* x_bf  = (ushort_t*)(p + 0);          // 25,165,824
  ushort_t* o_bf  = x_bf;                        // reuse: x dead after GEMM1
  ushort_t* qw_bf = (ushort_t*)(p + 25165824);   // 56,623,104
  ushort_t* pw_bf = (ushort_t*)(p + 81788928);   // 18,874,368
  ushort_t* qkv   = (ushort_t*)(p + 100663296);  // 75,497,472
  ushort_t* qh    = (ushort_t*)(p + 176160768);  // 25,165,824
  ushort_t* kh    = (ushort_t*)(p + 201326592);  // 25,165,824
  ushort_t* vtg   = (ushort_t*)(p + 226492416);  // 25,165,824 (V^T [B,H,D,L])

  cast_bf16<<<2048, 256, 0, stream>>>((const float4*)x,    (ushort4*)x_bf,  4096 * 3072 / 4);
  cast_bf16<<<2048, 256, 0, stream>>>((const float4*)qkvw, (ushort4*)qw_bf, 9216 * 3072 / 4);
  cast_bf16<<<2048, 256, 0, stream>>>((const float4*)pw,   (ushort4*)pw_bf, 3072 * 3072 / 4);

  // GEMM1: BN=288 -> grid 32x16 = 512 = 2.00 rounds at 1 blk/CU (r8 proven)
  gemmT<9, 1, 0><<<dim3(32, 16), 512, 0, stream>>>(x_bf, qw_bf, nullptr, qkv, 4096, 9216, 3072);
  norm_rope<<<dim3(64, 24), 256, 0, stream>>>(qkv, pe, qsc, ksc, qh, kh, vtg);
  attn_fwd<<<dim3(16, 48), 256, 0, stream>>>(qh, kh, vtg, o_bf);
  // GEMM2: BN=192 -> grid 16x16 = 256 = 1.00/CU (r8 proven)
  gemmT<6, 0, 1><<<dim3(16, 16), 512, 0, stream>>>(o_bf, pw_bf, pb, out, 4096, 3072, 3072);
}

// Round 14
// 512.257 us; speedup vs baseline: 1.0864x; 1.0128x over previous
//
#include <hip/hip_runtime.h>

typedef unsigned short ushort_t;
typedef unsigned short ushort8 __attribute__((ext_vector_type(8)));
typedef __bf16 bf16x8 __attribute__((ext_vector_type(8)));
typedef float f32x4 __attribute__((ext_vector_type(4)));
typedef float f32x16 __attribute__((ext_vector_type(16)));
typedef unsigned uint32x4 __attribute__((ext_vector_type(4)));

#define DEV __device__ __forceinline__

// ---------- helpers ----------
DEV ushort_t f2bf(float f) {
  unsigned u = __builtin_bit_cast(unsigned, f);
  u += 0x7FFFu + ((u >> 16) & 1u);   // RNE (no NaNs in this workload)
  return (ushort_t)(u >> 16);
}
DEV float bf2f(ushort_t u) {
  return __builtin_bit_cast(float, ((unsigned)u) << 16);
}
DEV void gload_lds16(const void* g, void* s) {
  __builtin_amdgcn_global_load_lds(
      (__attribute__((address_space(1))) void*)(size_t)g,
      (__attribute__((address_space(3))) void*)(size_t)s, 16, 0, 0);
}
DEV f32x4 mfma16(ushort8 a, ushort8 b, f32x4 c) {
  return __builtin_amdgcn_mfma_f32_16x16x32_bf16(
      __builtin_bit_cast(bf16x8, a), __builtin_bit_cast(bf16x8, b), c, 0, 0, 0);
}
DEV f32x16 mfma32(ushort8 a, ushort8 b, f32x16 c) {
  return __builtin_amdgcn_mfma_f32_32x32x16_bf16(
      __builtin_bit_cast(bf16x8, a), __builtin_bit_cast(bf16x8, b), c, 0, 0, 0);
}
DEV f32x16 zero16() {
  f32x16 z;
#pragma unroll
  for (int i = 0; i < 16; ++i) z[i] = 0.f;
  return z;
}
DEV unsigned cvtpk(float lo, float hi2) {  // u32 = {bf16(hi2), bf16(lo)}
  unsigned r;
  asm("v_cvt_pk_bf16_f32 %0, %1, %2" : "=v"(r) : "v"(lo), "v"(hi2));
  return r;
}
// x'[l] = l<32 ? x[l] : y[l-32];  y'[l] = l<32 ? x[l+32] : y[l]
DEV void swap32(unsigned &x, unsigned &y) {
#if __has_builtin(__builtin_amdgcn_permlane32_swap)
  auto t = __builtin_amdgcn_permlane32_swap(x, y, false, false);
  x = (unsigned)t[0];
  y = (unsigned)t[1];
#else
  unsigned xs = (unsigned)__shfl_xor((int)x, 32, 64);
  unsigned ys = (unsigned)__shfl_xor((int)y, 32, 64);
  bool h = (threadIdx.x & 63) >= 32;
  unsigned nx = h ? ys : x;
  unsigned ny = h ? y : xs;
  x = nx; y = ny;
#endif
}
DEV void barx() {  // raw barrier, no vmcnt drain; compiler memory fence
  asm volatile("" ::: "memory");
  __builtin_amdgcn_s_barrier();
  asm volatile("" ::: "memory");
}
#define GATE_VM0 asm volatile("s_waitcnt vmcnt(0)" ::: "memory")
#define GATE_VM8 asm volatile("s_waitcnt vmcnt(8)" ::: "memory")

// ---------- 1) fused f32 -> bf16 cast: 3 segments, one launch ----------
__global__ void cast_all(const float4* __restrict__ in0, ushort4* __restrict__ out0, int n0,
                         const float4* __restrict__ in1, ushort4* __restrict__ out1, int n1,
                         const float4* __restrict__ in2, ushort4* __restrict__ out2, int n2) {
  const int stride = gridDim.x * blockDim.x;
  const int t0 = blockIdx.x * blockDim.x + threadIdx.x;
  for (int i = t0; i < n0; i += stride) {
    float4 v = in0[i];
    out0[i] = make_ushort4(f2bf(v.x), f2bf(v.y), f2bf(v.z), f2bf(v.w));
  }
  for (int i = t0; i < n1; i += stride) {
    float4 v = in1[i];
    out1[i] = make_ushort4(f2bf(v.x), f2bf(v.y), f2bf(v.z), f2bf(v.w));
  }
  for (int i = t0; i < n2; i += stride) {
    float4 v = in2[i];
    out2[i] = make_ushort4(f2bf(v.x), f2bf(v.y), f2bf(v.z), f2bf(v.w));
  }
}

// ---------- 2) GEMM 256xBN, 16x16 frags, 1-barrier dbuf (r8/r13-proven) ----
// BN=288 for GEMM1 (grid 32x16=512 = 2.00 dispatch rounds at 1 blk/CU),
// BN=192 for GEMM2 (grid 16x16=256 = 1.00/CU). 8 waves 4M x 2N.
// Ledger: iter t stages t+1 -> buf db^1 BEFORE compute (issue overlaps
// MFMA; r12 showed stage-after-compute serializes and loses ~12%);
// compute tile t; vmcnt(0) (loads issued a full compute phase ago ->
// latency hidden); s_barrier. Chunk swizzle phys = log ^ (row&7), both
// sides (measured 0 conflicts). WPE=2: VGPR cap 256, acc=144 fits.
// Plateau note (r5-r12): 7 schedule variants bracket this at 223-260us;
// this config is the measured best. Wall/K-tile ~= MFMA-pipe + LDS-pipe
// (non-overlapping, barrier-lockstep) -- further gains need the m201-class
// fine interleave which 3 ports failed to reproduce in plain HIP here.
template <int NIW, int OUT_BF16, int ADD_BIAS>
__global__ __launch_bounds__(512, 2)
void gemmT(const ushort_t* __restrict__ A, const ushort_t* __restrict__ Bw,
           const float* __restrict__ bias, void* __restrict__ Cp,
           int M, int N, int K) {
  constexpr int BN = NIW * 32;            // 288 or 192
  constexpr int BCH_FULL = (BN * 8) / 512;      // full B staging instrs
  constexpr int BCH_TAIL = (BN * 8) % 512;      // leftover chunks (0 or 256)
  __shared__ ushort_t As[2][256 * 64];
  __shared__ ushort_t Bs[2][BN * 64];
  const int tid = threadIdx.x;
  const int w = tid >> 6, l = tid & 63;
  const int g = l >> 4, r = l & 15;
  const int wm = w >> 1, wn = w & 1;
  // XCD-chunked bijective swizzle (nwg % 8 == 0 for both grids)
  const int gx = gridDim.x;
  const int nwg = gx * gridDim.y;
  const int id = blockIdx.y * gx + blockIdx.x;
  const int swz = (id & 7) * (nwg >> 3) + (id >> 3);
  const int m0 = (swz / gx) * 256, n0 = (swz % gx) * BN;
  const int NT = K >> 6;

  // staging: instr i covers chunks [i*512, i*512+512); lane u -> row u>>3,
  // slot u&7; source k-chunk pre-swizzled (u&7)^(row&7)
  auto stA = [&](int i, int t, int b) {
    int u = i * 512 + tid;
    int row = u >> 3;
    gload_lds16(A + (size_t)(m0 + row) * K + t * 64 + (((u & 7) ^ (row & 7)) * 8),
                As[b] + (i * 512 + w * 64) * 8);
  };
  auto stB = [&](int i, int t, int b) {
    int u = i * 512 + tid;
    int row = u >> 3;
    gload_lds16(Bw + (size_t)(n0 + row) * K + t * 64 + (((u & 7) ^ (row & 7)) * 8),
                Bs[b] + (i * 512 + w * 64) * 8);
  };
  auto stage = [&](int t, int b) {
#pragma unroll
    for (int i = 0; i < 4; ++i) stA(i, t, b);
#pragma unroll
    for (int i = 0; i < BCH_FULL; ++i) stB(i, t, b);
    if (BCH_TAIL && w < (BCH_TAIL >> 6)) stB(BCH_FULL, t, b);
  };
  // 16x16 frag reads (measured 0 conflicts)
  auto rdA = [&](int b, int mi, int kk) -> ushort8 {
    int row = wm * 64 + mi * 16 + r;   // row&7 == r&7
    return *(const ushort8*)(As[b] + row * 64 + ((((kk << 2) + g) ^ (r & 7)) * 8));
  };
  auto rdB = [&](int b, int ni, int kk) -> ushort8 {
    int row = wn * (NIW * 16) + ni * 16 + r;   // NIW*16 % 8 == 0 -> row&7==r&7
    return *(const ushort8*)(Bs[b] + row * 64 + ((((kk << 2) + g) ^ (r & 7)) * 8));
  };

  f32x4 acc[4][NIW];
#pragma unroll
  for (int i = 0; i < 4; ++i)
#pragma unroll
    for (int j = 0; j < NIW; ++j) acc[i][j] = f32x4{0.f, 0.f, 0.f, 0.f};

  // prologue
  stage(0, 0);
  GATE_VM0;
  barx();

  for (int t = 0; t < NT; ++t) {
    const int db = t & 1;
    const bool pre = (t + 1 < NT);
    if (pre) stage(t + 1, db ^ 1);   // issue first: overlaps MFMA below
    asm volatile("" ::: "memory");
    __builtin_amdgcn_s_setprio(1);
#pragma unroll
    for (int kk = 0; kk < 2; ++kk) {
      ushort8 af[4];
#pragma unroll
      for (int mi = 0; mi < 4; ++mi) af[mi] = rdA(db, mi, kk);
#pragma unroll
      for (int ni = 0; ni < NIW; ++ni) {
        ushort8 b = rdB(db, ni, kk);
        acc[0][ni] = mfma16(af[0], b, acc[0][ni]);
        acc[1][ni] = mfma16(af[1], b, acc[1][ni]);
        acc[2][ni] = mfma16(af[2], b, acc[2][ni]);
        acc[3][ni] = mfma16(af[3], b, acc[3][ni]);
      }
    }
    __builtin_amdgcn_s_setprio(0);
    if (pre) GATE_VM0;   // t+1 landed; issued a full compute phase ago
    barx();              // buf db free for t+2's staging
  }

  // epilogue: D row = 4g+j (M-dim), col = r (N-dim)
#pragma unroll
  for (int mi = 0; mi < 4; ++mi) {
#pragma unroll
    for (int ni = 0; ni < NIW; ++ni) {
#pragma unroll
      for (int j = 0; j < 4; ++j) {
        int row = m0 + wm * 64 + mi * 16 + g * 4 + j;
        int col = n0 + wn * (NIW * 16) + ni * 16 + r;
        float v = acc[mi][ni][j];
        if (ADD_BIAS) v += bias[col];
        if (OUT_BF16)
          ((ushort_t*)Cp)[(size_t)row * N + col] = f2bf(v);
        else
          ((float*)Cp)[(size_t)row * N + col] = v;
      }
    }
  }
}

// ---------- 3) RMSNorm + RoPE (Q,K row-major) + V transpose to [B,H,D,L] ----
__global__ __launch_bounds__(256)
void norm_rope(const ushort_t* __restrict__ qkv, const float* __restrict__ pe,
               const float* __restrict__ qs, const float* __restrict__ ksc,
               ushort_t* __restrict__ qb, ushort_t* __restrict__ kb,
               ushort_t* __restrict__ vtg) {
  __shared__ ushort_t Vt_lds[128 * 64];   // [d][token], XOR-swizzled
  const int tid = threadIdx.x;
  const int w = tid >> 6, lane = tid & 63;
  const int tb = blockIdx.x, h = blockIdx.y;
  const int bl0 = tb * 64;
  const int b = bl0 >> 11, l0 = bl0 & 2047;
  const int i2 = lane * 2;

  const float sq0 = qs[i2], sq1 = qs[i2 + 1];
  const float sk0 = ksc[i2], sk1 = ksc[i2 + 1];
  const float QSC = 0.12751744f;  // log2(e) / sqrt(128): softmax in base-2

  for (int t = 0; t < 16; ++t) {
    const int bl = bl0 + w * 16 + t;
    const float4 p4 = *(const float4*)(pe + (size_t)bl * 256 + lane * 4);
    const size_t src = (size_t)bl * 9216 + h * 128 + i2;
    const size_t dst = ((size_t)(b * 24 + h) * 2048 + (bl & 2047)) * 128 + i2;
    {  // Q
      unsigned u = *(const unsigned*)(qkv + src);
      float x0 = bf2f((ushort_t)(u & 0xFFFFu)), x1 = bf2f((ushort_t)(u >> 16));
      float ss = x0 * x0 + x1 * x1;
#pragma unroll
      for (int mm = 32; mm; mm >>= 1) ss += __shfl_xor(ss, mm, 64);
      float rr = rsqrtf(ss * (1.f / 128.f) + 1e-6f);
      float y0 = x0 * rr * sq0, y1 = x1 * rr * sq1;
      float o0 = (p4.x * y0 + p4.y * y1) * QSC;
      float o1 = (p4.z * y0 + p4.w * y1) * QSC;
      *(unsigned*)(qb + dst) = (unsigned)f2bf(o0) | ((unsigned)f2bf(o1) << 16);
    }
    {  // K
      unsigned u = *(const unsigned*)(qkv + src + 3072);
      float x0 = bf2f((ushort_t)(u & 0xFFFFu)), x1 = bf2f((ushort_t)(u >> 16));
      float ss = x0 * x0 + x1 * x1;
#pragma unroll
      for (int mm = 32; mm; mm >>= 1) ss += __shfl_xor(ss, mm, 64);
      float rr = rsqrtf(ss * (1.f / 128.f) + 1e-6f);
      float y0 = x0 * rr * sk0, y1 = x1 * rr * sk1;
      float o0 = p4.x * y0 + p4.y * y1;
      float o1 = p4.z * y0 + p4.w * y1;
      *(unsigned*)(kb + dst) = (unsigned)f2bf(o0) | ((unsigned)f2bf(o1) << 16);
    }
  }

  {  // V -> LDS transposed
    const ushort_t* vsrc = qkv + (size_t)(bl0 + lane) * 9216 + 6144 + h * 128;
#pragma unroll
    for (int i = 0; i < 4; ++i) {
      int oct = w * 4 + i;
      ushort8 vv = *(const ushort8*)(vsrc + oct * 8);
#pragma unroll
      for (int j = 0; j < 8; ++j) {
        int d = oct * 8 + j;
        int ba = (d * 128 + lane * 2) ^ (j << 4);
        *(ushort_t*)((char*)Vt_lds + ba) = vv[j];
      }
    }
  }
  __syncthreads();

  {  // coalesced V^T rows to global [B,H,D,L]
    const int d = tid >> 1, half = tid & 1;
    ushort_t* orow = vtg + ((size_t)(b * 24 + h) * 128 + d) * 2048 + l0 + half * 32;
#pragma unroll
    for (int q = 0; q < 4; ++q) {
      int lb = d * 128 + half * 64 + q * 16;
      ushort8 vv = *(const ushort8*)((char*)Vt_lds + (lb ^ ((d & 7) << 4)));
      *(ushort8*)(orow + q * 8) = vv;
    }
  }
}

// ---------- 4) flash attention: swapped 32x32, double-buffered K/V ----------
// r8-proven. __launch_bounds__(256,2): VGPR cap 256, no spill; LDS 64KB,
// 2 blk/CU. Per tile: stage K(t+1),V(t+1) -> buf db^1; gate vm8 (t's 8
// landed, t+1's in flight across compute); barrier; QK^T; softmax;
// cvt_pk/permlane; PV; barrier (WAR guard).
__global__ __launch_bounds__(256, 2)
void attn_fwd(const ushort_t* __restrict__ qb, const ushort_t* __restrict__ kb,
              const ushort_t* __restrict__ vt, ushort_t* __restrict__ ob) {
  __shared__ ushort_t Ks[2][64 * 128];    // [key][d], phys chunk = log ^ (key&15)
  __shared__ ushort_t Vts[2][128 * 64];   // [d][key], phys chunk = log ^ (d&7)
  const int tid = threadIdx.x;
  const int w = tid >> 6, l = tid & 63;
  const int c = l & 31, hi = l >> 5;
  // XCD-chunked swizzle (768 blocks, 16 q-tiles x 48 bh)
  const int id = blockIdx.y * 16 + blockIdx.x;
  const int swz = (id & 7) * 96 + (id >> 3);
  const int bh = swz >> 4;
  const int q0 = (swz & 15) * 128 + w * 32;

  const ushort_t* qrow = qb + ((size_t)bh * 2048 + q0 + c) * 128;
  ushort8 qf[8];
#pragma unroll
  for (int s = 0; s < 8; ++s)
    qf[s] = *(const ushort8*)(qrow + s * 16 + hi * 8);

  f32x16 o[4];
#pragma unroll
  for (int dt = 0; dt < 4; ++dt) o[dt] = zero16();
  float m = -1e30f, lp = 0.f;   // m wave-uniform; lp row-c partial sum

  const ushort_t* kbase = kb + (size_t)bh * 2048 * 128;
  const ushort_t* vbase = vt + (size_t)bh * 128 * 2048;

  auto stage = [&](int t, int b) {
#pragma unroll
    for (int i = 0; i < 4; ++i) {
      int u = w * 256 + i * 64 + l;
      int kr = u >> 4, kc = (u & 15) ^ (kr & 15);
      gload_lds16(kbase + (size_t)(t * 64 + kr) * 128 + kc * 8,
                  Ks[b] + (w * 256 + i * 64) * 8);
      int vr = u >> 3, vc = (u & 7) ^ (vr & 7);
      gload_lds16(vbase + (size_t)vr * 2048 + t * 64 + vc * 8,
                  Vts[b] + (w * 256 + i * 64) * 8);
    }
  };

  stage(0, 0);   // prologue

  for (int t = 0; t < 32; ++t) {
    const int db = t & 1;
    if (t < 31) {
      stage(t + 1, db ^ 1);
      GATE_VM8;          // drains tile t's 8; t+1's stay in flight
    } else {
      GATE_VM0;
    }
    barx();

    // S^T = K . Q^T : two 32-key tiles, 8 d-steps of k=16
    f32x16 s0 = zero16(), s1 = zero16();
    __builtin_amdgcn_s_setprio(1);
#pragma unroll
    for (int ds = 0; ds < 8; ++ds) {
      int ch = (2 * ds + hi) ^ (c & 15);
      ushort8 k0 = *(const ushort8*)(Ks[db] + c * 128 + ch * 8);
      ushort8 k1 = *(const ushort8*)(Ks[db] + (32 + c) * 128 + ch * 8);
      s0 = mfma32(k0, qf[ds], s0);
      s1 = mfma32(k1, qf[ds], s1);
    }
    __builtin_amdgcn_s_setprio(0);

    // online softmax (base-2), wave-uniform max, defer THR=8; in-place s0/s1
    float pmax = s0[0];
#pragma unroll
    for (int rr = 1; rr < 16; ++rr) pmax = fmaxf(pmax, s0[rr]);
#pragma unroll
    for (int rr = 0; rr < 16; ++rr) pmax = fmaxf(pmax, s1[rr]);
    if (!__all(pmax <= m + 8.f)) {
      float wm2 = pmax;
#pragma unroll
      for (int d = 1; d < 64; d <<= 1) wm2 = fmaxf(wm2, __shfl_xor(wm2, d, 64));
      float mn = fmaxf(m, wm2);       // wave-uniform new max
      float fs = exp2f(m - mn);       // layout-independent rescale
      m = mn;
      lp *= fs;
#pragma unroll
      for (int dt = 0; dt < 4; ++dt)
#pragma unroll
        for (int e = 0; e < 16; ++e) o[dt][e] *= fs;
    }
    float rs = 0.f;
#pragma unroll
    for (int rr = 0; rr < 16; ++rr) { s0[rr] = exp2f(s0[rr] - m); rs += s0[rr]; }
#pragma unroll
    for (int rr = 0; rr < 16; ++rr) { s1[rr] = exp2f(s1[rr] - m); rs += s1[rr]; }
    lp += rs;

    // P -> A-frag words: 4 cvt_pk + 2 permlane32_swap per 16-key step (T12)
    uint32x4 pk[4];
#pragma unroll
    for (int ks = 0; ks < 2; ++ks) {
      unsigned a0 = cvtpk(s0[ks * 8 + 0], s0[ks * 8 + 1]);
      unsigned a1 = cvtpk(s0[ks * 8 + 2], s0[ks * 8 + 3]);
      unsigned a2 = cvtpk(s0[ks * 8 + 4], s0[ks * 8 + 5]);
      unsigned a3 = cvtpk(s0[ks * 8 + 6], s0[ks * 8 + 7]);
      swap32(a0, a2);
      swap32(a1, a3);
      pk[ks] = uint32x4{a0, a1, a2, a3};
    }
#pragma unroll
    for (int ks = 0; ks < 2; ++ks) {
      unsigned a0 = cvtpk(s1[ks * 8 + 0], s1[ks * 8 + 1]);
      unsigned a1 = cvtpk(s1[ks * 8 + 2], s1[ks * 8 + 3]);
      unsigned a2 = cvtpk(s1[ks * 8 + 4], s1[ks * 8 + 5]);
      unsigned a3 = cvtpk(s1[ks * 8 + 6], s1[ks * 8 + 7]);
      swap32(a0, a2);
      swap32(a1, a3);
      pk[2 + ks] = uint32x4{a0, a1, a2, a3};
    }

    // O += P . V
    __builtin_amdgcn_s_setprio(1);
#pragma unroll
    for (int dt = 0; dt < 4; ++dt) {
#pragma unroll
      for (int ks = 0; ks < 4; ++ks) {
        int ch = (2 * ks + hi) ^ (c & 7);
        ushort8 vf = *(const ushort8*)(Vts[db] + (32 * dt + c) * 64 + ch * 8);
        o[dt] = mfma32(__builtin_bit_cast(ushort8, pk[ks]), vf, o[dt]);
      }
    }
    __builtin_amdgcn_s_setprio(0);
    barx();   // WAR guard: next iter stages into buf db
  }

  // epilogue: lr lives at lane q (row c); O rows are crow(r,hi) -> shfl
  float lr = lp + __shfl_xor(lp, 32, 64);
  float rl = 1.f / lr;
  const int b = bh / 24, h = bh % 24;
  ushort_t* obase = ob + ((size_t)b * 2048 + q0) * 3072 + h * 128 + c;
#pragma unroll
  for (int rr = 0; rr < 16; ++rr) {
    int q = (rr & 3) + 8 * (rr >> 2) + 4 * hi;
    float os = __shfl(rl, q, 64);   // denominator of row q
#pragma unroll
    for (int dt = 0; dt < 4; ++dt)
      obase[(size_t)q * 3072 + dt * 32] = f2bf(o[dt][rr] * os);
  }
}

// ---------- launch ----------
extern "C" void kernel_launch(void* const* d_in, const int* in_sizes, int n_in,
                              void* d_out, int out_size, void* d_ws, size_t ws_size,
                              hipStream_t stream) {
  const float* x    = (const float*)d_in[0];
  const float* pe   = (const float*)d_in[1];
  const float* qkvw = (const float*)d_in[2];
  const float* pw   = (const float*)d_in[3];
  const float* pb   = (const float*)d_in[4];
  const float* qsc  = (const float*)d_in[5];
  const float* ksc  = (const float*)d_in[6];
  float* out = (float*)d_out;

  char* p = (char*)d_ws;
  ushort_t* x_bf  = (ushort_t*)(p + 0);          // 25,165,824
  ushort_t* o_bf  = x_bf;                        // reuse: x dead after GEMM1
  ushort_t* qw_bf = (ushort_t*)(p + 25165824);   // 56,623,104
  ushort_t* pw_bf = (ushort_t*)(p + 81788928);   // 18,874,368
  ushort_t* qkv   = (ushort_t*)(p + 100663296);  // 75,497,472
  ushort_t* qh    = (ushort_t*)(p + 176160768);  // 25,165,824
  ushort_t* kh    = (ushort_t*)(p + 201326592);  // 25,165,824
  ushort_t* vtg   = (ushort_t*)(p + 226492416);  // 25,165,824 (V^T [B,H,D,L])

  // fused cast: x, qkvw, pw -> bf16 in one launch (saves 2 launch gaps)
  cast_all<<<2048, 256, 0, stream>>>(
      (const float4*)x,    (ushort4*)x_bf,  4096 * 3072 / 4,
      (const float4*)qkvw, (ushort4*)qw_bf, 9216 * 3072 / 4,
      (const float4*)pw,   (ushort4*)pw_bf, 3072 * 3072 / 4);

  // GEMM1: BN=288 -> grid 32x16 = 512 (r8/r13 proven)
  gemmT<9, 1, 0><<<dim3(32, 16), 512, 0, stream>>>(x_bf, qw_bf, nullptr, qkv, 4096, 9216, 3072);
  norm_rope<<<dim3(64, 24), 256, 0, stream>>>(qkv, pe, qsc, ksc, qh, kh, vtg);
  attn_fwd<<<dim3(16, 48), 256, 0, stream>>>(qh, kh, vtg, o_bf);
  // GEMM2: BN=192 -> grid 16x16 = 256 = 1.00/CU (r8 proven)
  gemmT<6, 0, 1><<<dim3(16, 16), 512, 0, stream>>>(o_bf, pw_bf, pb, out, 4096, 3072, 3072);
}